// Round 3
// baseline (443.853 us; speedup 1.0000x reference)
//
#include <hip/hip_runtime.h>
#include <hip/hip_bf16.h>
#include <hip/hip_cooperative_groups.h>

namespace cg = cooperative_groups;

#define B_   4
#define S_   8192
#define D_   512
#define DFF_ 2048
#define K_TOP 1024

typedef unsigned short u16;
typedef __attribute__((ext_vector_type(8))) short bf16x8;
typedef __attribute__((ext_vector_type(4))) float floatx4;

// monotonic float -> uint key (order-preserving)
__device__ __forceinline__ unsigned f2key(float f){
    unsigned u = __float_as_uint(f);
    return (u & 0x80000000u) ? ~u : (u | 0x80000000u);
}
// fp32 -> bf16 round-to-nearest-even
__device__ __forceinline__ u16 f2b(float f){
    unsigned u = __float_as_uint(f);
    u = (u + 0x7FFFu + ((u >> 16) & 1u)) >> 16;
    return (u16)u;
}
// fast tanh-gelu via v_exp_f32
__device__ __forceinline__ float gelu_fast(float v){
    float u = 1.5957691216f * v + 0.0713548162726f * v * v * v;
    float e = __expf(u);
    return v - v / (e + 1.0f);
}
// async global->LDS, 16B per lane (wave-uniform base + lane*16)
__device__ __forceinline__ void gl_lds16(const void* gptr, void* lptr){
    auto g = (const __attribute__((address_space(1))) unsigned int*)((uintptr_t)gptr);
    auto l = (__attribute__((address_space(3))) unsigned int*)((uintptr_t)lptr);
    __builtin_amdgcn_global_load_lds(g, l, 16, 0, 0);
}

// GEMM operand tiles: [tile][kstep128][128 rows][16 chunks of 16B] bf16,
// chunk c of row r stored at slot (c ^ (r&15)) -> conflict-free ds_read_b128.

// ---------------- P0: router weights + copy-all x->out ---------------------
__device__ __forceinline__ void phase_router(int bx, int tid,
    const float4* __restrict__ x, float4* __restrict__ out,
    const float4* __restrict__ Wr4, const float* __restrict__ br,
    float* __restrict__ w_all)
{
    const int wv = tid >> 6, lane = tid & 63;
    const int t0 = bx * 64 + wv * 16;
    const float brv = br[0];
    const float4 wr0 = Wr4[lane], wr1 = Wr4[lane + 64];
    #pragma unroll
    for (int g = 0; g < 4; g++){
        float a[4];
        #pragma unroll
        for (int tt = 0; tt < 4; tt++){
            const int t = t0 + g * 4 + tt;
            const float4* xt = x + (size_t)t * 128;
            float4* ot = out + (size_t)t * 128;
            float4 v0 = xt[lane], v1 = xt[lane + 64];
            ot[lane] = v0; ot[lane + 64] = v1;
            a[tt] = v0.x*wr0.x + v0.y*wr0.y + v0.z*wr0.z + v0.w*wr0.w
                  + v1.x*wr1.x + v1.y*wr1.y + v1.z*wr1.z + v1.w*wr1.w;
        }
        #pragma unroll
        for (int off = 32; off > 0; off >>= 1){
            #pragma unroll
            for (int tt = 0; tt < 4; tt++) a[tt] += __shfl_down(a[tt], off, 64);
        }
        if (lane == 0){
            #pragma unroll
            for (int tt = 0; tt < 4; tt++) w_all[t0 + g * 4 + tt] = a[tt] + brv;
        }
    }
}

// ---------------- P1a: exact k-th largest per batch (256 thr) + compact ----
__device__ __forceinline__ void phase_kth(char* shm, int b, int tid,
    const float4* __restrict__ w_all4, int* __restrict__ counts,
    int* __restrict__ idx)
{
    unsigned* keys = (unsigned*)shm;                           // 32 KB
    unsigned (*hist)[256] = (unsigned(*)[256])(shm + 32768);   // 4 KB
    unsigned* sprefix = (unsigned*)(shm + 36864);
    int* sremk = (int*)(shm + 36872);
    int* lbase = (int*)(shm + 36880);
    const int wv = tid >> 6, lane = tid & 63;
    const float4* row4 = w_all4 + (size_t)b * (S_ / 4);

    #pragma unroll
    for (int i = 0; i < 8; i++){
        int j = tid + i * 256;
        float4 v = row4[j];
        keys[4*j+0] = f2key(v.x); keys[4*j+1] = f2key(v.y);
        keys[4*j+2] = f2key(v.z); keys[4*j+3] = f2key(v.w);
    }
    if (tid == 0){ *sprefix = 0u; *sremk = K_TOP; *lbase = 0; }
    __syncthreads();

    for (int pass = 3; pass >= 0; pass--){
        const int shift = pass * 8;
        #pragma unroll
        for (int i = 0; i < 4; i++) ((unsigned*)hist)[tid + i * 256] = 0u;
        __syncthreads();
        const unsigned mask_hi = (pass == 3) ? 0u : (0xFFFFFFFFu << (shift + 8));
        const unsigned pfx = *sprefix;
        #pragma unroll 8
        for (int i = 0; i < 32; i++){
            unsigned key = keys[tid + i * 256];
            if ((key & mask_hi) == pfx)
                atomicAdd(&hist[wv][(key >> shift) & 255u], 1u);
        }
        __syncthreads();
        if (wv == 0){
            const unsigned remk = (unsigned)*sremk;
            unsigned c[4];
            #pragma unroll
            for (int q = 0; q < 4; q++)
                c[q] = hist[0][4*lane+q] + hist[1][4*lane+q]
                     + hist[2][4*lane+q] + hist[3][4*lane+q];
            unsigned t = c[0] + c[1] + c[2] + c[3];
            unsigned ss = t;
            #pragma unroll
            for (int off = 1; off < 64; off <<= 1){
                unsigned o = __shfl_down(ss, off, 64);
                ss += (lane + off < 64) ? o : 0u;
            }
            const unsigned sgt = ss - t;
            unsigned suf[4];
            suf[3] = c[3] + sgt; suf[2] = c[2] + suf[3];
            suf[1] = c[1] + suf[2]; suf[0] = c[0] + suf[1];
            #pragma unroll
            for (int q = 0; q < 4; q++){
                unsigned nx = suf[q] - c[q];
                if (suf[q] >= remk && nx < remk){
                    *sprefix = pfx | ((unsigned)(4 * lane + q) << shift);
                    *sremk = (int)(remk - nx);
                }
            }
        }
        __syncthreads();
    }

    const unsigned thr = *sprefix;
    #pragma unroll 8
    for (int i = 0; i < 32; i++){
        int li = tid + i * 256;
        bool sel = keys[li] > thr;
        unsigned long long m = __ballot(sel);
        int wtot = (int)__popcll(m);
        if (wtot){
            int woff = 0;
            if (lane == 0) woff = atomicAdd(lbase, wtot);
            woff = __shfl(woff, 0, 64);
            if (sel){
                int pos = woff + (int)__popcll(m & ((1ull << lane) - 1ull));
                idx[b * 1024 + pos] = b * S_ + li;
            }
        }
    }
    __syncthreads();
    if (tid == 0) counts[b] = *lbase;
}

// ---------------- P1b: weight fp32 -> bf16 swizzled tiles ------------------
__device__ __forceinline__ void phase_conv(char* shm, int cv, int tid,
    const float* __restrict__ W1, const float* __restrict__ W2,
    u16* __restrict__ W1t, u16* __restrict__ W2t)
{
    const float* src; u16* dst; int R, C, ct, ks;
    if (cv < 64){ src = W1; dst = W1t; R = D_;   C = DFF_; ct = cv & 15;        ks = cv >> 4; }
    else        { src = W2; dst = W2t; R = DFF_; C = D_;   ct = (cv - 64) & 3;  ks = (cv - 64) >> 2; }
    u16 (*tile)[132] = (u16(*)[132])shm;
    #pragma unroll
    for (int it = 0; it < 64; it++){
        int lin = it * 256 + tid;
        int kk = lin >> 7, nn = lin & 127;
        tile[kk][nn] = f2b(src[(size_t)(ks * 128 + kk) * C + ct * 128 + nn]);
    }
    __syncthreads();
    u16* base = dst + (size_t)(ct * (R / 128) + ks) * 16384;
    const int r = tid >> 1, h = tid & 1;
    #pragma unroll
    for (int c = 0; c < 8; c++){
        int cl = h * 8 + c;
        bf16x8 bv;
        #pragma unroll
        for (int e = 0; e < 8; e++) bv[e] = (short)tile[cl * 8 + e][r];
        *(bf16x8*)&base[r * 128 + ((cl ^ (r & 15)) << 3)] = bv;
    }
}

// ---------------- P2: gather selected x rows -> bf16 tiles -----------------
__device__ __forceinline__ void phase_gather(int bx, int tid,
    const float* __restrict__ x, const int* __restrict__ idx,
    const int* __restrict__ counts, u16* __restrict__ XbT)
{
    const int mt = bx >> 4, s = (bx >> 2) & 3, q = bx & 3;
    const int cl = tid & 15, r16 = tid >> 4;
    u16* base = XbT + (size_t)(mt * 4 + s) * 16384;
    #pragma unroll
    for (int it = 0; it < 2; it++){
        int r = q * 32 + r16 + it * 16;
        int mg = mt * 128 + r;
        if ((mg & 1023) < counts[mg >> 10]){
            const float* xp = x + (size_t)idx[mg] * D_ + s * 128 + cl * 8;
            float4 v0 = *(const float4*)xp;
            float4 v1 = *(const float4*)(xp + 4);
            bf16x8 bv;
            bv[0]=(short)f2b(v0.x); bv[1]=(short)f2b(v0.y);
            bv[2]=(short)f2b(v0.z); bv[3]=(short)f2b(v0.w);
            bv[4]=(short)f2b(v1.x); bv[5]=(short)f2b(v1.y);
            bv[6]=(short)f2b(v1.z); bv[7]=(short)f2b(v1.w);
            *(bf16x8*)&base[r * 128 + ((cl ^ (r & 15)) << 3)] = bv;
        }
    }
}

// ---------------- P3: GEMM1 Ht = gelu(Xsel @ W1 + b1), 128x128, BK=64 ------
__device__ __forceinline__ void phase_ffn1(char* shm, int bx, int tid,
    const u16* __restrict__ XbT, const u16* __restrict__ W1t,
    const int* __restrict__ counts, const float* __restrict__ bias1,
    u16* __restrict__ Ht)
{
    const int task = (bx & 7) * 64 + (bx >> 3);     // XCD-chunked
    const int mBlk = task & 31, nBlk = task >> 5;
    const int lane = tid & 63, w = tid >> 6;
    const int wr = (w >> 1) * 64, wc = (w & 1) * 64;
    const int fr = lane & 15, quad = lane >> 4;
    u16* smem = (u16*)shm;

    const char* Abase = (const char*)(XbT + (size_t)mBlk * 4 * 16384);
    const char* Bbase = (const char*)(W1t + (size_t)nBlk * 4 * 16384);
    char* Al0 = shm + tid * 16;
    char* Bl0 = shm + 32768 + tid * 16;
    const int rr0 = tid >> 3, pp = tid & 7;

    auto stage = [&](const char* gbase, char* lb, int hs){
        const char* s0 = gbase + (size_t)(hs >> 1) * 32768;
        const int h = hs & 1;
        #pragma unroll
        for (int i = 0; i < 4; i++){
            int r = rr0 + i * 32;
            int pg = pp | (((h ^ (r >> 3)) & 1) << 3);
            gl_lds16(s0 + r * 256 + pg * 16, lb + i * 4096);
        }
    };
    stage(Abase, Al0, 0);
    stage(Bbase, Bl0, 0);

    floatx4 acc[4][4] = {};
    for (int hs = 0; hs < 8; hs++){
        __builtin_amdgcn_s_barrier();
        if (hs + 1 < 8){
            stage(Abase, Al0 + ((hs + 1) & 1) * 16384, hs + 1);
            stage(Bbase, Bl0 + ((hs + 1) & 1) * 16384, hs + 1);
            asm volatile("s_waitcnt vmcnt(8)" ::: "memory");
        } else {
            asm volatile("s_waitcnt vmcnt(0)" ::: "memory");
        }
        __builtin_amdgcn_sched_barrier(0);
        __builtin_amdgcn_s_barrier();
        const u16* Ab = smem + (hs & 1) * 8192;
        const u16* Bb = smem + 16384 + (hs & 1) * 8192;
        __builtin_amdgcn_s_setprio(1);
        #pragma unroll
        for (int ks2 = 0; ks2 < 2; ks2++){
            bf16x8 af[4], bf[4];
            #pragma unroll
            for (int i = 0; i < 4; i++){
                int r = wr + i * 16 + fr;
                af[i] = *(const bf16x8*)&Ab[r * 64 + (((ks2 * 4 + quad) ^ (r & 7)) << 3)];
            }
            #pragma unroll
            for (int j = 0; j < 4; j++){
                int r = wc + j * 16 + fr;
                bf[j] = *(const bf16x8*)&Bb[r * 64 + (((ks2 * 4 + quad) ^ (r & 7)) << 3)];
            }
            #pragma unroll
            for (int i = 0; i < 4; i++)
                #pragma unroll
                for (int j = 0; j < 4; j++)
                    acc[i][j] = __builtin_amdgcn_mfma_f32_16x16x32_bf16(af[i], bf[j], acc[i][j], 0, 0, 0);
        }
        __builtin_amdgcn_s_setprio(0);
    }

    float bj[4];
    #pragma unroll
    for (int j = 0; j < 4; j++) bj[j] = bias1[nBlk * 128 + wc + j * 16 + fr];

    __syncthreads();
    u16* Cs = smem;                  // 32KB: [128 r][128 c] swizzled
    #pragma unroll
    for (int i = 0; i < 4; i++){
        #pragma unroll
        for (int rg = 0; rg < 4; rg++){
            int r = wr + i * 16 + quad * 4 + rg;
            #pragma unroll
            for (int j = 0; j < 4; j++){
                int col = wc + j * 16 + fr;
                float v = gelu_fast(acc[i][j][rg] + bj[j]);
                Cs[r * 128 + ((((col >> 3) ^ (r & 15)) << 3) | (col & 7))] = f2b(v);
            }
        }
    }
    __syncthreads();
    const int r = tid >> 1, h = tid & 1;
    int mg = mBlk * 128 + r;
    if ((mg & 1023) < counts[mg >> 10]){
        u16* dstp = Ht + (((size_t)(mBlk * 2 + (r >> 6)) * 16 + nBlk) * 64 + (r & 63)) * 128;
        #pragma unroll
        for (int p = 0; p < 8; p++){
            int pc = h * 8 + p;
            *(bf16x8*)&dstp[pc << 3] = *(const bf16x8*)&Cs[r * 128 + (pc << 3)];
        }
    }
}

// ---------------- P4: GEMM2 out = (H @ W2 + b2) * w, 64x64, BK=128 ---------
__device__ __forceinline__ void phase_ffn2(char* shm, int bx, int tid,
    const u16* __restrict__ Ht, const u16* __restrict__ W2t,
    const int* __restrict__ counts, const int* __restrict__ idx,
    const float* __restrict__ w_all, const float* __restrict__ bias2,
    float* __restrict__ out)
{
    const int task = (bx & 7) * 64 + (bx >> 3);     // XCD gets whole nCol
    const int mBlk = task & 63, nCol = task >> 6;
    const int lane = tid & 63, w = tid >> 6;
    const int wr = (w >> 1) * 32, wc = (w & 1) * 32;
    const int fr = lane & 15, quad = lane >> 4;
    u16* smem = (u16*)shm;

    const char* Abase = (const char*)Ht + (size_t)mBlk * 262144;   // 16 ks x 16 KB
    const char* Bbase = (const char*)W2t + (size_t)(nCol >> 1) * 16 * 32768
                                         + (size_t)(nCol & 1) * 16384;
    char* Al0 = shm + tid * 16;
    char* Bl0 = shm + 32768 + tid * 16;

    auto stage2 = [&](int buf, int ks){
        const char* ga = Abase + (size_t)ks * 16384 + tid * 16;
        const char* gb = Bbase + (size_t)ks * 32768 + tid * 16;
        char* la = Al0 + buf * 16384;
        char* lb = Bl0 + buf * 16384;
        #pragma unroll
        for (int i = 0; i < 4; i++){
            gl_lds16(ga + i * 4096, la + i * 4096);
            gl_lds16(gb + i * 4096, lb + i * 4096);
        }
    };
    stage2(0, 0);

    floatx4 acc[2][2] = {};
    for (int ks = 0; ks < 16; ks++){
        __builtin_amdgcn_s_barrier();
        if (ks + 1 < 16){
            stage2((ks + 1) & 1, ks + 1);
            asm volatile("s_waitcnt vmcnt(8)" ::: "memory");
        } else {
            asm volatile("s_waitcnt vmcnt(0)" ::: "memory");
        }
        __builtin_amdgcn_sched_barrier(0);
        __builtin_amdgcn_s_barrier();
        const u16* Ab = smem + (ks & 1) * 8192;          // [64 r][128 k]
        const u16* Bb = smem + 16384 + (ks & 1) * 8192;  // [64 r][128 k]
        __builtin_amdgcn_s_setprio(1);
        #pragma unroll
        for (int ks2 = 0; ks2 < 4; ks2++){
            bf16x8 af[2], bf[2];
            #pragma unroll
            for (int i = 0; i < 2; i++){
                int r = wr + i * 16 + fr;
                af[i] = *(const bf16x8*)&Ab[r * 128 + (((ks2 * 4 + quad) ^ (r & 15)) << 3)];
            }
            #pragma unroll
            for (int j = 0; j < 2; j++){
                int r = wc + j * 16 + fr;
                bf[j] = *(const bf16x8*)&Bb[r * 128 + (((ks2 * 4 + quad) ^ (r & 15)) << 3)];
            }
            #pragma unroll
            for (int i = 0; i < 2; i++)
                #pragma unroll
                for (int j = 0; j < 2; j++)
                    acc[i][j] = __builtin_amdgcn_mfma_f32_16x16x32_bf16(af[i], bf[j], acc[i][j], 0, 0, 0);
        }
        __builtin_amdgcn_s_setprio(0);
    }

    float bj[2];
    #pragma unroll
    for (int j = 0; j < 2; j++) bj[j] = bias2[nCol * 64 + wc + j * 16 + fr];

    __syncthreads();
    float* Cs = (float*)shm;         // 16KB: [64 r][64 c]
    #pragma unroll
    for (int i = 0; i < 2; i++){
        #pragma unroll
        for (int rg = 0; rg < 4; rg++){
            int r = wr + i * 16 + quad * 4 + rg;
            #pragma unroll
            for (int j = 0; j < 2; j++)
                Cs[r * 64 + wc + j * 16 + fr] = acc[i][j][rg] + bj[j];
        }
    }
    __syncthreads();
    const int r = tid >> 2, q = tid & 3;
    int mg = mBlk * 64 + r;
    if ((mg & 1023) < counts[mg >> 10]){
        int token = idx[mg];
        float wt = w_all[token];
        float* op = out + (size_t)token * D_ + nCol * 64 + q * 16;
        const float4* cp = (const float4*)&Cs[r * 64 + q * 16];
        #pragma unroll
        for (int p = 0; p < 4; p++){
            float4 vv = cp[p];
            vv.x *= wt; vv.y *= wt; vv.z *= wt; vv.w *= wt;
            ((float4*)op)[p] = vv;
        }
    }
}

// ---------------- mega kernel (cooperative) --------------------------------
__global__ __launch_bounds__(256, 2) void mega_kernel(
    const float* x, const float* Wr, const float* br,
    const float* W1, const float* b1, const float* W2, const float* b2,
    float* out, float* w_all, int* counts, int* idx,
    u16* XbT, u16* W1t, u16* W2t, u16* Ht)
{
    __shared__ __align__(16) char shm[65536];
    cg::grid_group grid = cg::this_grid();
    const int bx = blockIdx.x, tid = threadIdx.x;

    phase_router(bx, tid, (const float4*)x, (float4*)out,
                 (const float4*)Wr, br, w_all);
    grid.sync();
    if (bx < 4)        phase_kth(shm, bx, tid, (const float4*)w_all, counts, idx);
    else if (bx < 132) phase_conv(shm, bx - 4, tid, W1, W2, W1t, W2t);
    grid.sync();
    phase_gather(bx, tid, x, idx, counts, XbT);
    grid.sync();
    phase_ffn1(shm, bx, tid, XbT, W1t, counts, b1, Ht);
    grid.sync();
    phase_ffn2(shm, bx, tid, Ht, W2t, counts, idx, w_all, b2, out);
}

// ---------------- fallback (non-cooperative) kernels -----------------------
__global__ __launch_bounds__(256) void k_router(
    const float* x, float* out, const float* Wr, const float* br, float* w_all)
{
    phase_router(blockIdx.x, threadIdx.x, (const float4*)x, (float4*)out,
                 (const float4*)Wr, br, w_all);
}
__global__ __launch_bounds__(256) void k_kthconv(
    const float* w_all, int* counts, int* idx,
    const float* W1, const float* W2, u16* W1t, u16* W2t)
{
    __shared__ __align__(16) char shm[65536];
    if (blockIdx.x < 4)
        phase_kth(shm, blockIdx.x, threadIdx.x, (const float4*)w_all, counts, idx);
    else
        phase_conv(shm, blockIdx.x - 4, threadIdx.x, W1, W2, W1t, W2t);
}
__global__ __launch_bounds__(256) void k_gather(
    const float* x, const int* idx, const int* counts, u16* XbT)
{
    phase_gather(blockIdx.x, threadIdx.x, x, idx, counts, XbT);
}
__global__ __launch_bounds__(256) void k_ffn1(
    const u16* XbT, const u16* W1t, const int* counts, const float* b1, u16* Ht)
{
    __shared__ __align__(16) char shm[65536];
    phase_ffn1(shm, blockIdx.x, threadIdx.x, XbT, W1t, counts, b1, Ht);
}
__global__ __launch_bounds__(256) void k_ffn2(
    const u16* Ht, const u16* W2t, const int* counts, const int* idx,
    const float* w_all, const float* b2, float* out)
{
    __shared__ __align__(16) char shm[65536];
    phase_ffn2(shm, blockIdx.x, threadIdx.x, Ht, W2t, counts, idx, w_all, b2, out);
}

extern "C" void kernel_launch(void* const* d_in, const int* in_sizes, int n_in,
                              void* d_out, int out_size, void* d_ws, size_t ws_size,
                              hipStream_t stream)
{
    const float* x  = (const float*)d_in[0];
    const float* Wr = (const float*)d_in[2];
    const float* br = (const float*)d_in[3];
    const float* W1 = (const float*)d_in[4];
    const float* b1 = (const float*)d_in[5];
    const float* W2 = (const float*)d_in[6];
    const float* b2 = (const float*)d_in[7];
    float* out = (float*)d_out;
    char* ws = (char*)d_ws;

    // workspace layout (bytes)
    float* w_all  = (float*)(ws + 0);          // 128 KB
    int*   counts = (int*)  (ws + 131072);     // 16 B
    int*   idx    = (int*)  (ws + 131136);     // 16 KB [4][1024]
    u16*   XbT    = (u16*)  (ws + 262144);     // 4 MB  [32][4][128][128]
    u16*   W1t    = (u16*)  (ws + 4456448);    // 2 MB  [16][4][128][128]
    u16*   W2t    = (u16*)  (ws + 6553600);    // 2 MB  [4][16][128][128]
    u16*   Ht     = (u16*)  (ws + 8650752);    // 16 MB [64][16][64][128]

    void* args[] = {
        (void*)&x, (void*)&Wr, (void*)&br, (void*)&W1, (void*)&b1,
        (void*)&W2, (void*)&b2, (void*)&out, (void*)&w_all,
        (void*)&counts, (void*)&idx, (void*)&XbT, (void*)&W1t,
        (void*)&W2t, (void*)&Ht };

    hipError_t e = hipLaunchCooperativeKernel((const void*)mega_kernel,
                       dim3(512), dim3(256), args, 0, stream);
    if (e != hipSuccess){
        // non-cooperative fallback: same phases as separate dispatches
        k_router <<<512, 256, 0, stream>>>(x, out, Wr, br, w_all);
        k_kthconv<<<132, 256, 0, stream>>>(w_all, counts, idx, W1, W2, W1t, W2t);
        k_gather <<<512, 256, 0, stream>>>(x, idx, counts, XbT);
        k_ffn1   <<<512, 256, 0, stream>>>(XbT, W1t, counts, b1, Ht);
        k_ffn2   <<<512, 256, 0, stream>>>(Ht, W2t, counts, idx, w_all, b2, out);
    }
}

// Round 4
// 195.377 us; speedup vs baseline: 2.2718x; 2.2718x over previous
//
#include <hip/hip_runtime.h>
#include <hip/hip_bf16.h>

#define B_   4
#define S_   8192
#define D_   512
#define DFF_ 2048
#define K_TOP 1024

typedef unsigned short u16;
typedef __attribute__((ext_vector_type(8))) short bf16x8;
typedef __attribute__((ext_vector_type(4))) float floatx4;

// monotonic float -> uint key (order-preserving)
__device__ __forceinline__ unsigned f2key(float f){
    unsigned u = __float_as_uint(f);
    return (u & 0x80000000u) ? ~u : (u | 0x80000000u);
}
// fp32 -> bf16 round-to-nearest-even
__device__ __forceinline__ u16 f2b(float f){
    unsigned u = __float_as_uint(f);
    u = (u + 0x7FFFu + ((u >> 16) & 1u)) >> 16;
    return (u16)u;
}
// fast tanh-gelu via v_exp_f32
__device__ __forceinline__ float gelu_fast(float v){
    float u = 1.5957691216f * v + 0.0713548162726f * v * v * v;
    float e = __expf(u);
    return v - v / (e + 1.0f);
}
// async global->LDS, 16B per lane (wave-uniform base + lane*16)
__device__ __forceinline__ void gl_lds16(const void* gptr, void* lptr){
    auto g = (const __attribute__((address_space(1))) unsigned int*)((uintptr_t)gptr);
    auto l = (__attribute__((address_space(3))) unsigned int*)((uintptr_t)lptr);
    __builtin_amdgcn_global_load_lds(g, l, 16, 0, 0);
}

// GEMM operand tiles: [tile][kstep128][128 rows][16 chunks of 16B] bf16,
// chunk c of row r at slot (c ^ (r&15)). BK=64 staging fetches the K-half's
// 8 chunks with pre-swizzled global addresses; LDS dest stays linear.

// ---------------- kernel 1: prep (router + hist + weight conv; NO out copy)
__global__ __launch_bounds__(256) void prep_kernel(
    const float* __restrict__ W1, const float* __restrict__ W2,
    u16* __restrict__ W1t, u16* __restrict__ W2t,
    const float4* __restrict__ x,
    const float4* __restrict__ Wr4, const float* __restrict__ br,
    float* __restrict__ w_all, unsigned* __restrict__ ghist)
{
    __shared__ __align__(16) unsigned char shmem[128 * 132 * 2]; // 33 KB union
    const int tid = threadIdx.x;
    const int bx = blockIdx.x;
    if (bx < 128){
        const float* src; u16* dst; int R, C, ct, ks;
        if (bx < 64){ src = W1; dst = W1t; R = D_;   C = DFF_; ct = bx & 15;        ks = bx >> 4; }
        else        { src = W2; dst = W2t; R = DFF_; C = D_;   ct = (bx - 64) & 3;  ks = (bx - 64) >> 2; }
        u16 (*tile)[132] = (u16(*)[132])shmem;
        #pragma unroll
        for (int it = 0; it < 64; it++){
            int lin = it * 256 + tid;
            int kk = lin >> 7, nn = lin & 127;
            tile[kk][nn] = f2b(src[(size_t)(ks * 128 + kk) * C + ct * 128 + nn]);
        }
        __syncthreads();
        u16* base = dst + (size_t)(ct * (R / 128) + ks) * 16384;
        const int r = tid >> 1, h = tid & 1;
        #pragma unroll
        for (int c = 0; c < 8; c++){
            int cl = h * 8 + c;
            bf16x8 bv;
            #pragma unroll
            for (int e = 0; e < 8; e++) bv[e] = (short)tile[cl * 8 + e][r];
            *(bf16x8*)&base[r * 128 + ((cl ^ (r & 15)) << 3)] = bv;
        }
    } else {
        unsigned* hist = (unsigned*)shmem;
        if (tid < 256) hist[tid] = 0u;
        __syncthreads();
        const int wb = bx - 128;                  // 0..511, 128 blocks/batch
        const int wv = tid >> 6, lane = tid & 63;
        const int t0 = wb * 64 + wv * 16;
        const float brv = br[0];
        const float4 wr0 = Wr4[lane], wr1 = Wr4[lane + 64];
        #pragma unroll
        for (int g = 0; g < 4; g++){
            float a[4];
            #pragma unroll
            for (int tt = 0; tt < 4; tt++){
                const float4* xt = x + (size_t)(t0 + g * 4 + tt) * 128;
                float4 v0 = xt[lane], v1 = xt[lane + 64];
                a[tt] = v0.x*wr0.x + v0.y*wr0.y + v0.z*wr0.z + v0.w*wr0.w
                      + v1.x*wr1.x + v1.y*wr1.y + v1.z*wr1.z + v1.w*wr1.w;
            }
            #pragma unroll
            for (int off = 32; off > 0; off >>= 1){
                #pragma unroll
                for (int tt = 0; tt < 4; tt++) a[tt] += __shfl_down(a[tt], off, 64);
            }
            if (lane == 0){
                #pragma unroll
                for (int tt = 0; tt < 4; tt++){
                    float wt = a[tt] + brv;
                    w_all[t0 + g * 4 + tt] = wt;
                    atomicAdd(&hist[f2key(wt) >> 24], 1u);
                }
            }
        }
        __syncthreads();
        if (tid < 256) ghist[wb * 256 + tid] = hist[tid];   // non-atomic row
    }
}

// ------- kernel 2: exact k-th largest per batch, wave0-scan radix ----------
__global__ __launch_bounds__(1024) void kth_compact_kernel(
    const float4* __restrict__ w_all4, const unsigned* __restrict__ ghist,
    int* __restrict__ counts, unsigned* __restrict__ thr_out,
    int* __restrict__ idx)
{
    __shared__ unsigned keys[S_];
    __shared__ unsigned hist[4][256];
    __shared__ unsigned sprefix;
    __shared__ int sremk;
    __shared__ int lbase;
    const int b = blockIdx.x, tid = threadIdx.x;
    const int wv = tid >> 6, lane = tid & 63;
    const float4* row4 = w_all4 + (size_t)b * (S_ / 4);

    #pragma unroll
    for (int i = 0; i < 2; i++){
        int j = tid + i * 1024;
        float4 v = row4[j];
        keys[4*j+0] = f2key(v.x); keys[4*j+1] = f2key(v.y);
        keys[4*j+2] = f2key(v.z); keys[4*j+3] = f2key(v.w);
    }
    // coarse top-byte hist: 4 row-groups of 32 prep-rows each -> hist[q][bin]
    {
        const int bin = tid & 255, q = tid >> 8;
        unsigned s = 0;
        const unsigned* gh = ghist + (size_t)(b * 128 + q * 32) * 256 + bin;
        #pragma unroll 8
        for (int j = 0; j < 32; j++) s += gh[j * 256];
        hist[q][bin] = s;
    }
    if (tid == 0){ sprefix = 0u; sremk = K_TOP; lbase = 0; }
    __syncthreads();

    for (int pass = 3; pass >= 0; pass--){
        const int shift = pass * 8;
        if (pass < 3){
            ((unsigned*)hist)[tid] = 0u;
            __syncthreads();
            const unsigned mask_hi = 0xFFFFFFFFu << (shift + 8);
            const unsigned pfx = sprefix;
            #pragma unroll
            for (int i = 0; i < 8; i++){
                unsigned key = keys[tid + i * 1024];
                if ((key & mask_hi) == pfx)
                    atomicAdd(&hist[wv & 3][(key >> shift) & 255u], 1u);
            }
            __syncthreads();
        }
        if (wv == 0){
            const unsigned remk = (unsigned)sremk;
            const unsigned pfx = sprefix;
            unsigned c[4];
            #pragma unroll
            for (int q = 0; q < 4; q++)
                c[q] = hist[0][4*lane+q] + hist[1][4*lane+q]
                     + hist[2][4*lane+q] + hist[3][4*lane+q];
            unsigned t = c[0] + c[1] + c[2] + c[3];
            unsigned ss = t;
            #pragma unroll
            for (int off = 1; off < 64; off <<= 1){
                unsigned o = __shfl_down(ss, off, 64);
                ss += (lane + off < 64) ? o : 0u;
            }
            const unsigned sgt = ss - t;
            unsigned suf[4];
            suf[3] = c[3] + sgt; suf[2] = c[2] + suf[3];
            suf[1] = c[1] + suf[2]; suf[0] = c[0] + suf[1];
            #pragma unroll
            for (int q = 0; q < 4; q++){
                unsigned nx = suf[q] - c[q];
                if (suf[q] >= remk && nx < remk){
                    sprefix = pfx | ((unsigned)(4 * lane + q) << shift);
                    sremk = (int)(remk - nx);
                }
            }
        }
        __syncthreads();
    }

    const unsigned thr = sprefix;
    #pragma unroll
    for (int i = 0; i < 8; i++){
        int li = tid + i * 1024;
        bool sel = keys[li] > thr;
        unsigned long long m = __ballot(sel);
        int wtot = (int)__popcll(m);
        if (wtot){
            int woff = 0;
            if (lane == 0) woff = atomicAdd(&lbase, wtot);
            woff = __shfl(woff, 0, 64);
            if (sel){
                int pos = woff + (int)__popcll(m & ((1ull << lane) - 1ull));
                idx[b * 1024 + pos] = b * S_ + li;
            }
        }
    }
    __syncthreads();
    if (tid == 0){ counts[b] = lbase; thr_out[b] = thr; }
}

// --- kernel 3: gather selected x rows -> bf16 tiled+swizzled ---------------
__global__ __launch_bounds__(256) void gather_kernel(
    const float* __restrict__ x, const int* __restrict__ idx,
    const int* __restrict__ counts, u16* __restrict__ XbT)
{
    const int mt = blockIdx.x, s = blockIdx.y;
    const int cl = threadIdx.x & 15, r16 = threadIdx.x >> 4;
    u16* base = XbT + (size_t)(mt * 4 + s) * 16384;
    #pragma unroll
    for (int it = 0; it < 8; it++){
        int r = r16 + it * 16;
        int mg = mt * 128 + r;
        if ((mg & 1023) < counts[mg >> 10]){
            const float* xp = x + (size_t)idx[mg] * D_ + s * 128 + cl * 8;
            float4 v0 = *(const float4*)xp;
            float4 v1 = *(const float4*)(xp + 4);
            bf16x8 bv;
            bv[0]=(short)f2b(v0.x); bv[1]=(short)f2b(v0.y);
            bv[2]=(short)f2b(v0.z); bv[3]=(short)f2b(v0.w);
            bv[4]=(short)f2b(v1.x); bv[5]=(short)f2b(v1.y);
            bv[6]=(short)f2b(v1.z); bv[7]=(short)f2b(v1.w);
            *(bf16x8*)&base[r * 128 + ((cl ^ (r & 15)) << 3)] = bv;
        }
    }
}

// tail copy: nTok unselected tokens starting at tBase, run by all 4 waves
__device__ __forceinline__ void tail_copy(
    const float4* __restrict__ x, float4* __restrict__ out,
    const float* __restrict__ w_all, const unsigned* __restrict__ thr,
    int tBase, int perWave, int tid)
{
    const int wv = tid >> 6, lane = tid & 63;
    const int t0 = tBase + wv * perWave;
    for (int tt = 0; tt < perWave; tt++){
        int t = t0 + tt;
        if (f2key(w_all[t]) <= thr[t >> 13]){
            const float4* xs = x + (size_t)t * 128;
            float4* od = out + (size_t)t * 128;
            od[lane]      = xs[lane];
            od[lane + 64] = xs[lane + 64];
        }
    }
}

// --- kernel 4: GEMM1 Ht = gelu(Xsel @ W1 + b1), 128x128, BK=64 dbuf --------
// grid: 512 blocks; each block also tail-copies 32 tokens (0..16383)
__global__ __launch_bounds__(256) void ffn1_kernel(
    const u16* __restrict__ XbT, const u16* __restrict__ W1t,
    const int* __restrict__ counts, const float* __restrict__ bias1,
    u16* __restrict__ Ht,
    const float4* __restrict__ x, float4* __restrict__ out,
    const float* __restrict__ w_all, const unsigned* __restrict__ thr)
{
    __shared__ __align__(16) u16 smem[32768];     // A:2x16KB | B:2x16KB
    const int tid = threadIdx.x;
    const int bx = blockIdx.x;
    const int mBlk = bx & 31, nBlk = bx >> 5;
    const int lane = tid & 63, w = tid >> 6;
    const int wr = (w >> 1) * 64, wc = (w & 1) * 64;
    const int fr = lane & 15, quad = lane >> 4;

    const char* Abase = (const char*)(XbT + (size_t)mBlk * 4 * 16384);
    const char* Bbase = (const char*)(W1t + (size_t)nBlk * 4 * 16384);
    char* Al0 = (char*)smem + tid * 16;
    char* Bl0 = (char*)(smem + 16384) + tid * 16;
    const int rr0 = tid >> 3, pp = tid & 7;

    auto stage = [&](const char* gbase, char* lb, int hs){
        const char* s0 = gbase + (size_t)(hs >> 1) * 32768;
        const int h = hs & 1;
        #pragma unroll
        for (int i = 0; i < 4; i++){
            int r = rr0 + i * 32;
            int pg = pp | (((h ^ (r >> 3)) & 1) << 3);
            gl_lds16(s0 + r * 256 + pg * 16, lb + i * 4096);
        }
    };

    stage(Abase, Al0, 0);
    stage(Bbase, Bl0, 0);

    floatx4 acc[4][4] = {};
    for (int hs = 0; hs < 8; hs++){
        __builtin_amdgcn_s_barrier();            // WAR: prev-iter reads done
        if (hs + 1 < 8){
            stage(Abase, Al0 + ((hs + 1) & 1) * 16384, hs + 1);
            stage(Bbase, Bl0 + ((hs + 1) & 1) * 16384, hs + 1);
            asm volatile("s_waitcnt vmcnt(8)" ::: "memory");
        } else {
            asm volatile("s_waitcnt vmcnt(0)" ::: "memory");
        }
        __builtin_amdgcn_sched_barrier(0);
        __builtin_amdgcn_s_barrier();            // all waves' stage(hs) landed
        const u16* Ab = smem + (hs & 1) * 8192;
        const u16* Bb = smem + 16384 + (hs & 1) * 8192;
        __builtin_amdgcn_s_setprio(1);
        #pragma unroll
        for (int ks2 = 0; ks2 < 2; ks2++){
            bf16x8 af[4], bf[4];
            #pragma unroll
            for (int i = 0; i < 4; i++){
                int r = wr + i * 16 + fr;
                af[i] = *(const bf16x8*)&Ab[r * 64 + (((ks2 * 4 + quad) ^ (r & 7)) << 3)];
            }
            #pragma unroll
            for (int j = 0; j < 4; j++){
                int r = wc + j * 16 + fr;
                bf[j] = *(const bf16x8*)&Bb[r * 64 + (((ks2 * 4 + quad) ^ (r & 7)) << 3)];
            }
            #pragma unroll
            for (int i = 0; i < 4; i++)
                #pragma unroll
                for (int j = 0; j < 4; j++)
                    acc[i][j] = __builtin_amdgcn_mfma_f32_16x16x32_bf16(af[i], bf[j], acc[i][j], 0, 0, 0);
        }
        __builtin_amdgcn_s_setprio(0);
    }

    float bj[4];
    #pragma unroll
    for (int j = 0; j < 4; j++) bj[j] = bias1[nBlk * 128 + wc + j * 16 + fr];

    __syncthreads();
    u16* Cs = smem;                  // 32KB: [128 r][128 c] swizzled
    #pragma unroll
    for (int i = 0; i < 4; i++){
        #pragma unroll
        for (int rg = 0; rg < 4; rg++){
            int r = wr + i * 16 + quad * 4 + rg;
            #pragma unroll
            for (int j = 0; j < 4; j++){
                int col = wc + j * 16 + fr;
                float v = gelu_fast(acc[i][j][rg] + bj[j]);
                Cs[r * 128 + ((((col >> 3) ^ (r & 15)) << 3) | (col & 7))] = f2b(v);
            }
        }
    }
    __syncthreads();
    const int r = tid >> 1, h = tid & 1;
    int mg = mBlk * 128 + r;
    if ((mg & 1023) < counts[mg >> 10]){
        u16* dstp = Ht + (((size_t)(mBlk * 2 + (r >> 6)) * 16 + nBlk) * 64 + (r & 63)) * 128;
        #pragma unroll
        for (int p = 0; p < 8; p++){
            int pc = h * 8 + p;
            *(bf16x8*)&dstp[pc << 3] = *(const bf16x8*)&Cs[r * 128 + (pc << 3)];
        }
    }
    // tail: 32 unselected tokens per block, tokens [0, 16384)
    tail_copy(x, out, w_all, thr, bx * 32, 8, tid);
}

// --- kernel 5: GEMM2 out = (H @ W2 + b2) * w, 64x128, BK=64 dbuf -----------
// grid: 256 blocks; each block also tail-copies 64 tokens (16384..32767)
__global__ __launch_bounds__(256) void ffn2_kernel(
    const u16* __restrict__ Ht, const u16* __restrict__ W2t,
    const int* __restrict__ counts, const int* __restrict__ idx,
    const float* __restrict__ w_all, const float* __restrict__ bias2,
    float* __restrict__ out,
    const float4* __restrict__ x, const unsigned* __restrict__ thr)
{
    __shared__ __align__(16) u16 smem[24576];     // A:2x8KB | B:2x16KB
    const int tid = threadIdx.x;
    const int bx = blockIdx.x;
    const int mBlk = bx & 63, nBlk = bx >> 6;
    const int lane = tid & 63, w = tid >> 6;
    const int wr = (w >> 1) * 32, wc = (w & 1) * 64;
    const int fr = lane & 15, quad = lane >> 4;

    const char* Abase = (const char*)(Ht + (size_t)mBlk * 16 * 8192);
    const char* Bbase = (const char*)(W2t + (size_t)nBlk * 16 * 16384);
    char* Al0 = (char*)smem + tid * 16;
    char* Bl0 = (char*)(smem + 8192) + tid * 16;
    const int rr0 = tid >> 3, pp = tid & 7;

    auto stage = [&](int buf, int hs){
        const int h = hs & 1;
        {   // A: [64][64] = 8KB, 2 loads
            const char* s0 = Abase + (size_t)(hs >> 1) * 16384;
            char* l = Al0 + buf * 8192;
            #pragma unroll
            for (int i = 0; i < 2; i++){
                int r = rr0 + i * 32;
                int pg = pp | (((h ^ (r >> 3)) & 1) << 3);
                gl_lds16(s0 + r * 256 + pg * 16, l + i * 4096);
            }
        }
        {   // B: [128][64] = 16KB, 4 loads
            const char* s0 = Bbase + (size_t)(hs >> 1) * 32768;
            char* l = Bl0 + buf * 16384;
            #pragma unroll
            for (int i = 0; i < 4; i++){
                int r = rr0 + i * 32;
                int pg = pp | (((h ^ (r >> 3)) & 1) << 3);
                gl_lds16(s0 + r * 256 + pg * 16, l + i * 4096);
            }
        }
    };

    stage(0, 0);
    floatx4 acc[2][4] = {};
    for (int hs = 0; hs < 32; hs++){
        __builtin_amdgcn_s_barrier();            // WAR: prev-iter reads done
        if (hs + 1 < 32){
            stage((hs + 1) & 1, hs + 1);
            asm volatile("s_waitcnt vmcnt(6)" ::: "memory");
        } else {
            asm volatile("s_waitcnt vmcnt(0)" ::: "memory");
        }
        __builtin_amdgcn_sched_barrier(0);
        __builtin_amdgcn_s_barrier();            // all waves' stage(hs) landed
        const u16* Ab = smem + (hs & 1) * 4096;
        const u16* Bb = smem + 8192 + (hs & 1) * 8192;
        __builtin_amdgcn_s_setprio(1);
        #pragma unroll
        for (int ks2 = 0; ks2 < 2; ks2++){
            bf16x8 af[2], bf[4];
            #pragma unroll
            for (int i = 0; i < 2; i++){
                int r = wr + i * 16 + fr;
                af[i] = *(const bf16x8*)&Ab[r * 64 + (((ks2 * 4 + quad) ^ (r & 7)) << 3)];
            }
            #pragma unroll
            for (int j = 0; j < 4; j++){
                int r = wc + j * 16 + fr;
                bf[j] = *(const bf16x8*)&Bb[r * 64 + (((ks2 * 4 + quad) ^ (r & 7)) << 3)];
            }
            #pragma unroll
            for (int i = 0; i < 2; i++)
                #pragma unroll
                for (int j = 0; j < 4; j++)
                    acc[i][j] = __builtin_amdgcn_mfma_f32_16x16x32_bf16(af[i], bf[j], acc[i][j], 0, 0, 0);
        }
        __builtin_amdgcn_s_setprio(0);
    }

    float bj[4];
    #pragma unroll
    for (int j = 0; j < 4; j++) bj[j] = bias2[nBlk * 128 + wc + j * 16 + fr];

    __syncthreads();
    float* Cs = (float*)smem;        // 32KB: [64 r][128 c]
    #pragma unroll
    for (int i = 0; i < 2; i++){
        #pragma unroll
        for (int rg = 0; rg < 4; rg++){
            int r = wr + i * 16 + quad * 4 + rg;
            #pragma unroll
            for (int j = 0; j < 4; j++)
                Cs[r * 128 + wc + j * 16 + fr] = acc[i][j][rg] + bj[j];
        }
    }
    __syncthreads();
    const int r = tid >> 2, q = tid & 3;
    int mg = mBlk * 64 + r;
    if ((mg & 1023) < counts[mg >> 10]){
        int token = idx[mg];
        float wt = w_all[token];
        float* op = out + (size_t)token * D_ + nBlk * 128 + q * 32;
        const float4* cp = (const float4*)&Cs[r * 128 + q * 32];
        #pragma unroll
        for (int p = 0; p < 8; p++){
            float4 vv = cp[p];
            vv.x *= wt; vv.y *= wt; vv.z *= wt; vv.w *= wt;
            ((float4*)op)[p] = vv;
        }
    }
    // tail: 64 unselected tokens per block, tokens [16384, 32768)
    tail_copy(x, (float4*)out, w_all, thr, 16384 + bx * 64, 16, tid);
}

extern "C" void kernel_launch(void* const* d_in, const int* in_sizes, int n_in,
                              void* d_out, int out_size, void* d_ws, size_t ws_size,
                              hipStream_t stream)
{
    const float* x  = (const float*)d_in[0];
    const float* Wr = (const float*)d_in[2];
    const float* br = (const float*)d_in[3];
    const float* W1 = (const float*)d_in[4];
    const float* b1 = (const float*)d_in[5];
    const float* W2 = (const float*)d_in[6];
    const float* b2 = (const float*)d_in[7];
    float* out = (float*)d_out;
    char* ws = (char*)d_ws;

    // workspace layout (bytes)
    float*    w_all  = (float*)   (ws + 0);         // 128 KB
    int*      counts = (int*)     (ws + 131072);    // 16 B (per-batch)
    unsigned* thr    = (unsigned*)(ws + 131088);    // 16 B (per-batch key thr)
    int*      idx    = (int*)     (ws + 131136);    // 16 KB [4][1024]
    unsigned* ghist  = (unsigned*)(ws + 163840);    // 512 KB [512][256]
    u16*      XbT    = (u16*)     (ws + 720896);    // 4 MB  [32][4][128][128]
    u16*      W1t    = (u16*)     (ws + 4915200);   // 2 MB  [16][4][128][128]
    u16*      W2t    = (u16*)     (ws + 7012352);   // 2 MB  [4][16][128][128]
    u16*      Ht     = (u16*)     (ws + 9109504);   // 16 MB [64][16][64][128]

    prep_kernel<<<640, 256, 0, stream>>>(
        W1, W2, W1t, W2t, (const float4*)x,
        (const float4*)Wr, br, w_all, ghist);
    kth_compact_kernel<<<B_, 1024, 0, stream>>>(
        (const float4*)w_all, ghist, counts, thr, idx);
    gather_kernel<<<dim3(32, 4), 256, 0, stream>>>(x, idx, counts, XbT);
    ffn1_kernel<<<512, 256, 0, stream>>>(
        XbT, W1t, counts, b1, Ht, (const float4*)x, (float4*)out, w_all, thr);
    ffn2_kernel<<<256, 256, 0, stream>>>(
        Ht, W2t, counts, idx, w_all, b2, out, (const float4*)x, thr);
}